// Round 6
// baseline (187.150 us; speedup 1.0000x reference)
//
#include <hip/hip_runtime.h>
#include <cstdint>
#include <cstddef>

typedef int int4v __attribute__((ext_vector_type(4)));
typedef signed char schar;

#define DEVI __device__ __forceinline__

DEVI void load_lds16(const void* g, void* l) {
  __builtin_amdgcn_global_load_lds(
      (const __attribute__((address_space(1))) void*)g,
      (__attribute__((address_space(3))) void*)l, 16, 0, 0);
}

#define SB0() __builtin_amdgcn_sched_barrier(0)
#define BAR() __builtin_amdgcn_s_barrier()
#define LGKM(n)                                                   \
  do {                                                            \
    asm volatile("s_waitcnt lgkmcnt(" #n ")" ::: "memory");       \
    SB0();                                                        \
  } while (0)
#define VMW(n)                                                    \
  do {                                                            \
    asm volatile("s_waitcnt vmcnt(" #n ")" ::: "memory");         \
    SB0();                                                        \
  } while (0)

// ---- pack int32 -> int8, linear (4 elems/thread) ----
__global__ __launch_bounds__(256) void pack_i8(const int* __restrict__ src,
                                               signed char* __restrict__ dst,
                                               int n4) {
  int i = blockIdx.x * 256 + threadIdx.x;
  if (i >= n4) return;
  int4v v = ((const int4v*)src)[i];
  int p = (v.x & 255) | ((v.y & 255) << 8) | ((v.z & 255) << 16) | (v.w << 24);
  ((int*)dst)[i] = p;
}

// ---- pack + transpose: w[K][N] int32 -> wT[N][K] int8, 64x64 LDS tiles ----
__global__ __launch_bounds__(256) void pack_wT(const int* __restrict__ w,
                                               signed char* __restrict__ wT,
                                               int K, int N) {
  __shared__ signed char t[64][68];
  int n0 = blockIdx.x * 64, k0 = blockIdx.y * 64;
  int tr = threadIdx.x >> 6, tc = threadIdx.x & 63;
#pragma unroll
  for (int i = 0; i < 16; ++i) {
    int r = i * 4 + tr;
    t[r][tc] = (signed char)w[(size_t)(k0 + r) * N + n0 + tc];
  }
  __syncthreads();
#pragma unroll
  for (int i = 0; i < 16; ++i) {
    int r = i * 4 + tr;
    wT[(size_t)(n0 + r) * K + k0 + tc] = t[tc][r];
  }
}

// ---- 256x256 4-deep-pipelined i8 GEMM: C[M,N] = A[M,K] * BT[N,K]^T ----
// 8 waves (2Mx4N), 128x64 out/wave, acc[8][4]=128 AGPR.
// BK=64 B (one 16x16x64 K-step). FOUR LDS buffers (4 x 32 KB = 128 KiB):
// stage tile T+2 during tile T; VMW(4) at tile end waits only tile T+1's
// loads (issued a full tile earlier -> latency amortized; vmcnt NEVER 0
// in-loop = T4/AITER pattern). Stage issued FIRST (earliest VMEM entry).
// No forced lgkm(0) before MFMA: compiler's fine-grained lgkmcnt drains
// reads UNDER the MFMA cluster. lgkm(0) only before the barrier (WAR has
// a full spare tile of slack with 4 buffers).
// Swizzle (64-B rows, 4 slots of 16 B): lds slot = g ^ ((row>>1)&3);
// fragment reads then hit each bank exactly 2x per wave (free).
template <int EPI>
__global__ __launch_bounds__(512, 2) void gemmP(
    const schar* __restrict__ A, const schar* __restrict__ BT,
    int M, int N, int K, const int* __restrict__ bias_i,
    const float* __restrict__ alphaP, const float* __restrict__ betaP,
    const float* __restrict__ bias_f, schar* __restrict__ outQ,
    float* __restrict__ outF) {
  extern __shared__ schar lds[];

  const int tid = threadIdx.x;
  const int wid = tid >> 6, lane = tid & 63;
  const int wr = wid >> 2, wc = wid & 3;  // 2M x 4N waves
  const int l16 = lane & 15, l4 = lane >> 4;

  // XCD-bijective block swizzle (nwg % 8 == 0 for both GEMMs)
  const int gx = gridDim.x;
  const int nwg = gx * gridDim.y;
  const int bid = blockIdx.y * gx + blockIdx.x;
  const int swz = (bid & 7) * (nwg >> 3) + (bid >> 3);
  const int rowBase = (swz / gx) * 256;
  const int colBase = (swz % gx) * 256;
  const int NT = K >> 6;  // 64-B K-tiles

  // pin scalar params; drain SMEM before counted waits
  const float alpha = alphaP[0];
  const float beta = (EPI == 0) ? betaP[0] : 0.f;
  asm volatile("" ::"s"(alpha), "s"(beta));
  LGKM(0);

  // staging source pointers (pre-swizzled global slot; LDS dest linear).
  // Round c covers LDS offsets c*8192 + tid*16 within a 16 KB region.
  const schar* gA[2];
  const schar* gB[2];
#pragma unroll
  for (int c = 0; c < 2; ++c) {
    int o = c * 8192 + tid * 16;
    int r = o >> 6;                       // row 0..255 (64-B rows)
    int g = ((o >> 4) & 3) ^ ((r >> 1) & 3);
    gA[c] = A + (size_t)(rowBase + r) * K + g * 16;
    gB[c] = BT + (size_t)(colBase + r) * K + g * 16;
  }

  auto stage = [&](int buf, int t) {
    schar* d = lds + buf * 32768 + wid * 1024;
    load_lds16(gA[0] + (size_t)t * 64, d);
    load_lds16(gA[1] + (size_t)t * 64, d + 8192);
    load_lds16(gB[0] + (size_t)t * 64, d + 16384);
    load_lds16(gB[1] + (size_t)t * 64, d + 24576);
  };

  // fragment read offset: row = base + l16; slot = l4 ^ ((l16>>1)&3)
  // (base>>1 is a multiple of 8, so (row>>1)&3 == (l16>>1)&3: lane-const)
  const int slotc = (l4 ^ ((l16 >> 1) & 3)) * 16 + l16 * 64;

  int4v acc[8][4] = {};
  int4v aF[8], bF[4];

#define RDA(Ab)                                                   \
  _Pragma("unroll") for (int mi = 0; mi < 8; ++mi) aF[mi] =       \
      *(const int4v*)((Ab) + wr * 8192 + mi * 1024 + slotc)
#define RDB(Bb)                                                   \
  _Pragma("unroll") for (int ni = 0; ni < 4; ++ni) bF[ni] =       \
      *(const int4v*)((Bb) + wc * 4096 + ni * 1024 + slotc)
#define MMALL()                                                        \
  do {                                                                 \
    __builtin_amdgcn_s_setprio(1);                                     \
    _Pragma("unroll") for (int mi = 0; mi < 8; ++mi)                   \
        _Pragma("unroll") for (int ni = 0; ni < 4; ++ni) acc[mi][ni] = \
        __builtin_amdgcn_mfma_i32_16x16x64_i8(aF[mi], bF[ni],          \
                                              acc[mi][ni], 0, 0, 0);   \
    __builtin_amdgcn_s_setprio(0);                                     \
  } while (0)

  // prologue: stage tiles 0,1; wait tile 0 landed (tile 1 in flight)
  stage(0, 0);
  stage(1, 1);
  VMW(4);
  BAR();

  for (int T = 0; T < NT; ++T) {
    const int cb = T & 3;
    const schar* Ab = lds + cb * 32768;
    const schar* Bb = Ab + 16384;

    if (T + 2 < NT) stage((T + 2) & 3, T + 2);  // earliest VMEM entry
    RDA(Ab);
    RDB(Bb);
    MMALL();  // compiler interleaves fine-grained lgkm waits under MFMA

    LGKM(0);  // own reads of buf cb done before leaving tile
    if (T + 2 < NT) {
      VMW(4);  // tile T+1 resident; T+2's 4 loads stay in flight
    } else {
      VMW(0);  // pipeline drain (last 2 tiles only)
    }
    BAR();
  }

  // ---- epilogue; C/D frag: col = lane&15, row = (lane>>4)*4 + j ----
  if (EPI == 0) {
#pragma unroll
    for (int MI = 0; MI < 8; ++MI) {
      int row = rowBase + wr * 128 + MI * 16 + l4 * 4;
#pragma unroll
      for (int NI = 0; NI < 4; ++NI) {
        int col = colBase + wc * 64 + NI * 16 + l16;
        float bt = (float)bias_i[col] * beta;
#pragma unroll
        for (int j = 0; j < 4; ++j) {
          float h = (float)acc[MI][NI][j] * alpha + bt;
          h = fmaxf(h, 0.f);
          h = rintf(h);  // numpy round-half-even
          h = fminf(h, 127.f);
          outQ[(size_t)(row + j) * N + col] = (schar)h;
        }
      }
    }
  } else {
#pragma unroll
    for (int MI = 0; MI < 8; ++MI) {
      int row = rowBase + wr * 128 + MI * 16 + l4 * 4;
#pragma unroll
      for (int NI = 0; NI < 4; ++NI) {
        int col = colBase + wc * 64 + NI * 16 + l16;
        float bv = bias_f[col];
#pragma unroll
        for (int j = 0; j < 4; ++j)
          outF[(size_t)(row + j) * N + col] =
              (float)acc[MI][NI][j] * alpha + bv;
      }
    }
  }
#undef RDA
#undef RDB
#undef MMALL
}

extern "C" void kernel_launch(void* const* d_in, const int* in_sizes, int n_in,
                              void* d_out, int out_size, void* d_ws,
                              size_t ws_size, hipStream_t stream) {
  const int M = 16384, H = 1024, I = 4096;  // B*S = 16384
  const int* hidden = (const int*)d_in[0];
  const int* w_fc = (const int*)d_in[1];
  const int* b_fc = (const int*)d_in[2];
  const float* alpha_fc = (const float*)d_in[3];
  const float* beta_fc = (const float*)d_in[4];
  const int* w_proj = (const int*)d_in[5];
  const float* b_proj = (const float*)d_in[6];
  const float* alpha_proj = (const float*)d_in[7];
  float* out = (float*)d_out;

  signed char* hq = (signed char*)d_ws;     // [M][I]  64 MB
  signed char* aP = hq + (size_t)M * I;     // [M][H]  16 MB
  signed char* wfcT = aP + (size_t)M * H;   // [I][H]   4 MB (w_fc^T)
  signed char* wpT = wfcT + (size_t)I * H;  // [H][I]   4 MB (w_proj^T)

  hipFuncSetAttribute((const void*)gemmP<0>,
                      hipFuncAttributeMaxDynamicSharedMemorySize, 131072);
  hipFuncSetAttribute((const void*)gemmP<1>,
                      hipFuncAttributeMaxDynamicSharedMemorySize, 131072);

  pack_i8<<<(M * H / 4 + 255) / 256, 256, 0, stream>>>(hidden, aP, M * H / 4);
  pack_wT<<<dim3(I / 64, H / 64), 256, 0, stream>>>(w_fc, wfcT, H, I);
  pack_wT<<<dim3(H / 64, I / 64), 256, 0, stream>>>(w_proj, wpT, I, H);

  gemmP<0><<<dim3(I / 256, M / 256), 512, 131072, stream>>>(
      aP, wfcT, M, I, H, b_fc, alpha_fc, beta_fc, nullptr, hq, nullptr);
  gemmP<1><<<dim3(H / 256, M / 256), 512, 131072, stream>>>(
      hq, wpT, M, H, I, nullptr, alpha_proj, nullptr, b_proj, nullptr, out);
}

// Round 7
// 179.342 us; speedup vs baseline: 1.0435x; 1.0435x over previous
//
#include <hip/hip_runtime.h>
#include <cstdint>
#include <cstddef>

typedef int int4v __attribute__((ext_vector_type(4)));
typedef signed char schar;

#define DEVI __device__ __forceinline__

DEVI void load_lds16(const void* g, void* l) {
  __builtin_amdgcn_global_load_lds(
      (const __attribute__((address_space(1))) void*)g,
      (__attribute__((address_space(3))) void*)l, 16, 0, 0);
}

// Bare waits: NO sched_barrier, NO memory clobber (m141/m201 lesson —
// pins defeat the compiler's fine-grained lgkmcnt interleave).
#define BAR() __builtin_amdgcn_s_barrier()
#define LGKM(n) asm volatile("s_waitcnt lgkmcnt(" #n ")")
#define VMW(n) asm volatile("s_waitcnt vmcnt(" #n ")")

// ---- pack int32 -> int8, linear (4 elems/thread) ----
__global__ __launch_bounds__(256) void pack_i8(const int* __restrict__ src,
                                               signed char* __restrict__ dst,
                                               int n4) {
  int i = blockIdx.x * 256 + threadIdx.x;
  if (i >= n4) return;
  int4v v = ((const int4v*)src)[i];
  int p = (v.x & 255) | ((v.y & 255) << 8) | ((v.z & 255) << 16) | (v.w << 24);
  ((int*)dst)[i] = p;
}

// ---- pack + transpose: w[K][N] int32 -> wT[N][K] int8, 64x64 LDS tiles ----
__global__ __launch_bounds__(256) void pack_wT(const int* __restrict__ w,
                                               signed char* __restrict__ wT,
                                               int K, int N) {
  __shared__ signed char t[64][68];
  int n0 = blockIdx.x * 64, k0 = blockIdx.y * 64;
  int tr = threadIdx.x >> 6, tc = threadIdx.x & 63;
#pragma unroll
  for (int i = 0; i < 16; ++i) {
    int r = i * 4 + tr;
    t[r][tc] = (signed char)w[(size_t)(k0 + r) * N + n0 + tc];
  }
  __syncthreads();
#pragma unroll
  for (int i = 0; i < 16; ++i) {
    int r = i * 4 + tr;
    wT[(size_t)(n0 + r) * K + k0 + tc] = t[tc][r];
  }
}

// ---- 256x256 8-phase i8 GEMM (R2 schedule, pins removed) ----
// 8 waves (2Mx4N), 128x64 out/wave, BK=128 B (2 K-steps of 16x16x64).
// Per K-tile T (buffers c=T&1, o=c^1), 4 phases, each {ds-reads | 1 stage
// | [lgkm hint] | BAR | lgkm0 | 16 MFMA | BAR}; vmcnt(4) once per tile
// (B of T+2 stays in flight -> vmcnt never 0 in-loop).
// WAR safety: each phase's lgkm(0) precedes its closing barrier, so all
// tile-T reads drain block-wide before T+2's staging overwrites that LDS.
template <int EPI>
__global__ __launch_bounds__(512, 2) void gemm8(
    const schar* __restrict__ A, const schar* __restrict__ BT,
    int M, int N, int K, const int* __restrict__ bias_i,
    const float* __restrict__ alphaP, const float* __restrict__ betaP,
    const float* __restrict__ bias_f, schar* __restrict__ outQ,
    float* __restrict__ outF) {
  extern __shared__ schar lds[];
  constexpr int ATILE = 32768;  // 256 rows x 128 B

  const int tid = threadIdx.x;
  const int wid = tid >> 6, lane = tid & 63;
  const int wr = wid >> 2, wc = wid & 3;
  const int l16 = lane & 15, l4 = lane >> 4;

  // XCD-bijective block swizzle (nwg % 8 == 0 for both GEMMs)
  const int gx = gridDim.x;
  const int nwg = gx * gridDim.y;
  const int bid = blockIdx.y * gx + blockIdx.x;
  const int swz = (bid & 7) * (nwg >> 3) + (bid >> 3);
  const int rowBase = (swz / gx) * 256;
  const int colBase = (swz % gx) * 256;
  const int NT = K >> 7;

  // pin scalar params; drain SMEM before counted lgkm waits
  const float alpha = alphaP[0];
  const float beta = (EPI == 0) ? betaP[0] : 0.f;
  asm volatile("" ::"s"(alpha), "s"(beta));
  LGKM(0);

  // staging (pre-swizzled global source; LDS dest linear)
  const int off0 = tid * 16, off1 = 8192 + tid * 16;
  const int rl0 = off0 >> 7, rl1 = off1 >> 7;
  const int gs0 = ((off0 >> 4) & 7) ^ (rl0 & 7);
  const int gs1 = ((off1 >> 4) & 7) ^ (rl1 & 7);
  const schar* gA0 = A + (size_t)(rowBase + rl0) * K + gs0 * 16;
  const schar* gA1 = A + (size_t)(rowBase + rl1) * K + gs1 * 16;
  const schar* gB0 = BT + (size_t)(colBase + rl0) * K + gs0 * 16;
  const schar* gB1 = BT + (size_t)(colBase + rl1) * K + gs1 * 16;
  const size_t hstep = (size_t)128 * K;
  const int wb = wid * 1024;

  auto stA = [&](int buf, int t, int h) {
    schar* d = lds + buf * ATILE + h * 16384 + wb;
    load_lds16(gA0 + (size_t)t * 128 + (size_t)h * hstep, d);
    load_lds16(gA1 + (size_t)t * 128 + (size_t)h * hstep, d + 8192);
  };
  auto stB = [&](int buf, int t, int h) {
    schar* d = lds + 2 * ATILE + buf * ATILE + h * 16384 + wb;
    load_lds16(gB0 + (size_t)t * 128 + (size_t)h * hstep, d);
    load_lds16(gB1 + (size_t)t * 128 + (size_t)h * hstep, d + 8192);
  };

  int4v acc[8][4] = {};
  int4v a[4][2], b0[2][2], b1[2][2];

  // ds_read fragments; row&7 == l16&7, so swizzle slot is lane-const
#define LDA(QM, Ab)                                                         \
  do {                                                                      \
    _Pragma("unroll") for (int mi = 0; mi < 4; ++mi)                        \
        _Pragma("unroll") for (int kk = 0; kk < 2; ++kk) a[mi][kk] =        \
        *(const int4v*)((Ab) + (wr * 128 + (QM)*64 + mi * 16 + l16) * 128 + \
                        (((kk * 4) + l4) ^ (l16 & 7)) * 16);                \
  } while (0)
#define LDB(B, QN, Bb)                                                      \
  do {                                                                      \
    _Pragma("unroll") for (int ni = 0; ni < 2; ++ni)                        \
        _Pragma("unroll") for (int kk = 0; kk < 2; ++kk) (B)[ni][kk] =      \
        *(const int4v*)((Bb) + (wc * 64 + ((QN)*2 + ni) * 16 + l16) * 128 + \
                        (((kk * 4) + l4) ^ (l16 & 7)) * 16);                \
  } while (0)
#define MMQ(QM, QN, B)                                                       \
  do {                                                                       \
    __builtin_amdgcn_s_setprio(1);                                           \
    _Pragma("unroll") for (int kk = 0; kk < 2; ++kk)                         \
        _Pragma("unroll") for (int mi = 0; mi < 4; ++mi)                     \
            _Pragma("unroll") for (int ni = 0; ni < 2; ++ni)                 \
                acc[(QM)*4 + mi][(QN)*2 + ni] =                              \
        __builtin_amdgcn_mfma_i32_16x16x64_i8(                               \
            a[mi][kk], (B)[ni][kk], acc[(QM)*4 + mi][(QN)*2 + ni], 0, 0, 0); \
    __builtin_amdgcn_s_setprio(0);                                           \
  } while (0)

  // prologue: tile0 fully, tile1 B halves; vmcnt(4) leaves B1 in flight
  stA(0, 0, 0);
  stA(0, 0, 1);
  stB(0, 0, 0);
  stB(0, 0, 1);
  if (NT > 1) {
    stB(1, 1, 0);
    stB(1, 1, 1);
    VMW(4);
  } else {
    VMW(0);
  }
  BAR();

  for (int T = 0; T < NT; ++T) {
    const int cb = T & 1, ob = cb ^ 1;
    const schar* Ac = lds + cb * ATILE;
    const schar* Bc = lds + 2 * ATILE + cb * ATILE;

    // P0: 12 reads, stage A(T+1)h0, MFMA Q00
    LDA(0, Ac);
    LDB(b0, 0, Bc);
    if (T + 1 < NT) stA(ob, T + 1, 0);
    LGKM(8);  // pre-drain hint (m201 pattern for 12-read phases)
    BAR();
    LGKM(0);
    MMQ(0, 0, b0);
    BAR();
    // P1: 4 reads, stage A(T+1)h1, MFMA Q01
    LDB(b1, 1, Bc);
    if (T + 1 < NT) stA(ob, T + 1, 1);
    BAR();
    LGKM(0);
    MMQ(0, 1, b1);
    BAR();
    // P2: 8 reads, stage B(T+2)h0, MFMA Q10
    LDA(1, Ac);
    if (T + 2 < NT) stB(cb, T + 2, 0);
    BAR();
    LGKM(0);
    MMQ(1, 0, b0);
    BAR();
    // P3: stage B(T+2)h1, MFMA Q11, counted vmcnt
    if (T + 2 < NT) stB(cb, T + 2, 1);
    BAR();
    MMQ(1, 1, b1);
    if (T + 2 < NT) {
      VMW(4);  // A(T+1)+B(T+1) retired; B(T+2) stays in flight
    } else if (T + 1 < NT) {
      VMW(0);  // drain tail
    }
    BAR();
  }

  // ---- epilogue; C/D frag: col = lane&15, row = (lane>>4)*4 + j ----
  if (EPI == 0) {
#pragma unroll
    for (int MI = 0; MI < 8; ++MI) {
      int row = rowBase + wr * 128 + MI * 16 + l4 * 4;
#pragma unroll
      for (int NI = 0; NI < 4; ++NI) {
        int col = colBase + wc * 64 + NI * 16 + l16;
        float bt = (float)bias_i[col] * beta;
#pragma unroll
        for (int j = 0; j < 4; ++j) {
          float h = (float)acc[MI][NI][j] * alpha + bt;
          h = fmaxf(h, 0.f);
          h = rintf(h);  // numpy round-half-even
          h = fminf(h, 127.f);
          outQ[(size_t)(row + j) * N + col] = (schar)h;
        }
      }
    }
  } else {
#pragma unroll
    for (int MI = 0; MI < 8; ++MI) {
      int row = rowBase + wr * 128 + MI * 16 + l4 * 4;
#pragma unroll
      for (int NI = 0; NI < 4; ++NI) {
        int col = colBase + wc * 64 + NI * 16 + l16;
        float bv = bias_f[col];
#pragma unroll
        for (int j = 0; j < 4; ++j)
          outF[(size_t)(row + j) * N + col] =
              (float)acc[MI][NI][j] * alpha + bv;
      }
    }
  }
#undef LDA
#undef LDB
#undef MMQ
}

extern "C" void kernel_launch(void* const* d_in, const int* in_sizes, int n_in,
                              void* d_out, int out_size, void* d_ws,
                              size_t ws_size, hipStream_t stream) {
  const int M = 16384, H = 1024, I = 4096;  // B*S = 16384
  const int* hidden = (const int*)d_in[0];
  const int* w_fc = (const int*)d_in[1];
  const int* b_fc = (const int*)d_in[2];
  const float* alpha_fc = (const float*)d_in[3];
  const float* beta_fc = (const float*)d_in[4];
  const int* w_proj = (const int*)d_in[5];
  const float* b_proj = (const float*)d_in[6];
  const float* alpha_proj = (const float*)d_in[7];
  float* out = (float*)d_out;

  signed char* hq = (signed char*)d_ws;     // [M][I]  64 MB
  signed char* aP = hq + (size_t)M * I;     // [M][H]  16 MB
  signed char* wfcT = aP + (size_t)M * H;   // [I][H]   4 MB (w_fc^T)
  signed char* wpT = wfcT + (size_t)I * H;  // [H][I]   4 MB (w_proj^T)

  hipFuncSetAttribute((const void*)gemm8<0>,
                      hipFuncAttributeMaxDynamicSharedMemorySize, 131072);
  hipFuncSetAttribute((const void*)gemm8<1>,
                      hipFuncAttributeMaxDynamicSharedMemorySize, 131072);

  pack_i8<<<(M * H / 4 + 255) / 256, 256, 0, stream>>>(hidden, aP, M * H / 4);
  pack_wT<<<dim3(I / 64, H / 64), 256, 0, stream>>>(w_fc, wfcT, H, I);
  pack_wT<<<dim3(H / 64, I / 64), 256, 0, stream>>>(w_proj, wpT, I, H);

  gemm8<0><<<dim3(I / 256, M / 256), 512, 131072, stream>>>(
      aP, wfcT, M, I, H, b_fc, alpha_fc, beta_fc, nullptr, hq, nullptr);
  gemm8<1><<<dim3(H / 256, M / 256), 512, 131072, stream>>>(
      hq, wpT, M, H, I, nullptr, alpha_proj, nullptr, b_proj, nullptr, out);
}